// Round 15
// baseline (222.573 us; speedup 1.0000x reference)
//
#include <hip/hip_runtime.h>
#include <hip/hip_fp16.h>
#include <math.h>

#define NN 50000
#define EE 800000
#define DD 128
#define SLOPE 0.2f

typedef __attribute__((ext_vector_type(8))) _Float16 half8;  // 8 fp16 (4 VGPRs)
typedef __attribute__((ext_vector_type(4))) float f32x4;     // MFMA acc

static __device__ __forceinline__ ushort f2h(float f) {
    __half h = __float2half(f);
    return *reinterpret_cast<ushort*>(&h);
}
static __device__ __forceinline__ __half2 u2h2(unsigned int u) {
    __half2 h;
    *reinterpret_cast<unsigned int*>(&h) = u;
    return h;
}
static __device__ __forceinline__ unsigned int h22u(__half2 h) {
    return *reinterpret_cast<unsigned int*>(&h);
}

// ---------------- CSR build ----------------
__global__ void k_degree(const int* __restrict__ dstv, int* __restrict__ deg) {
    int i = blockIdx.x * blockDim.x + threadIdx.x;
    if (i < EE) atomicAdd(&deg[dstv[i]], 1);
}

__global__ void k_blocksum(const int* __restrict__ deg, int* __restrict__ bsum) {
    int t = threadIdx.x;
    int idx = blockIdx.x * 256 + t;
    int v = (idx < NN) ? deg[idx] : 0;
#pragma unroll
    for (int m = 1; m < 64; m <<= 1) v += __shfl_xor(v, m, 64);
    __shared__ int part[4];
    if ((t & 63) == 0) part[t >> 6] = v;
    __syncthreads();
    if (t == 0) bsum[blockIdx.x] = part[0] + part[1] + part[2] + part[3];
}

__global__ void k_scan_bsum(const int* __restrict__ bsum, int* __restrict__ boff, int nb) {
    __shared__ int sd[2][256];
    int t = threadIdx.x;
    int v = (t < nb) ? bsum[t] : 0;
    sd[0][t] = v;
    __syncthreads();
    int s = 0;
    for (int off = 1; off < 256; off <<= 1) {
        int x = sd[s][t];
        if (t >= off) x += sd[s][t - off];
        sd[s ^ 1][t] = x;
        s ^= 1;
        __syncthreads();
    }
    if (t < nb) boff[t] = sd[s][t] - v;  // exclusive
}

__global__ void k_scan_final(const int* __restrict__ deg, const int* __restrict__ boff,
                             int* __restrict__ offs, int* __restrict__ cursor) {
    __shared__ int sd[2][256];
    int t = threadIdx.x;
    int idx = blockIdx.x * 256 + t;
    int v = (idx < NN) ? deg[idx] : 0;
    sd[0][t] = v;
    __syncthreads();
    int s = 0;
    for (int off = 1; off < 256; off <<= 1) {
        int x = sd[s][t];
        if (t >= off) x += sd[s][t - off];
        sd[s ^ 1][t] = x;
        s ^= 1;
        __syncthreads();
    }
    int incl = sd[s][t];
    int base = boff[blockIdx.x];
    if (idx < NN) {
        offs[idx + 1] = base + incl;
        cursor[idx] = base + incl - v;  // segment start
    }
    if (idx == 0) offs[0] = 0;
}

__global__ void k_scatter(const int* __restrict__ srcv, const int* __restrict__ dstv,
                          int* __restrict__ cursor, int* __restrict__ csr_src) {
    int i = blockIdx.x * blockDim.x + threadIdx.x;
    if (i < EE) {
        int p = atomicAdd(&cursor[dstv[i]], 1);
        csr_src[p] = srcv[i];
    }
}

// ---------------- weight convert: Wt[i][n][k] = fp16(W_i[k][n]) ----------------
__global__ __launch_bounds__(256) void k_wconvert(
    const float* __restrict__ W0, const float* __restrict__ W1, const float* __restrict__ W2,
    const float* __restrict__ W3, const float* __restrict__ W4, const float* __restrict__ W5,
    ushort* __restrict__ Wt) {
    int idx = blockIdx.x * 256 + threadIdx.x;  // 6*16384
    int i = idx >> 14;
    int r = idx & 16383;
    int n = r >> 7;
    int k = r & 127;
    const float* Ws[6] = {W0, W1, W2, W3, W4, W5};
    Wt[idx] = f2h(Ws[i][k * DD + n]);
}

// ---------------- MFMA 3-matrix GEMM (fp16 in, fp32 acc), 64-row tiles ----------------
// block=256 (4 waves), each wave: 16 rows x 128 cols. K=128. grid=(NN+63)/64=782
// (~3.05 blocks/CU -> balanced, vs 391 = 1.53 block-waves with idle tail).
// LDS-transpose epilogue for coalesced half8 stores.
template <int XBF>
__global__ __launch_bounds__(256) void k_gemm3m(
    const float* __restrict__ Xf,     // [NN][128] fp32   (XBF=0)
    const ushort* __restrict__ Xb,    // [NN][128] fp16   (XBF=1)
    const ushort* __restrict__ Wt,    // [3][128][128] fp16, [n][k] layout
    ushort* __restrict__ O0b,         // xl fp16
    ushort* __restrict__ O1b,         // xr fp16
    ushort* __restrict__ O2b) {       // lin fp16
    __shared__ ushort wsh[128 * 136];  // weights tile; reused as epilogue transpose buffer
    int t = threadIdx.x;
    int wid = t >> 6, lane = t & 63;
    int m0 = blockIdx.x * 64 + wid * 16;
    int qrow = lane & 15, kg = lane >> 4;

    // A fragments: 4 k-steps, row = m0 + qrow
    half8 afrag[4];
    {
        int row = m0 + qrow;
        row = (row < NN) ? row : (NN - 1);  // clamp (stores predicated)
#pragma unroll
        for (int ks = 0; ks < 4; ks++) {
            if (XBF) {
                afrag[ks] = *reinterpret_cast<const half8*>(
                    Xb + (size_t)row * DD + ks * 32 + kg * 8);
            } else {
                const float* p = Xf + (size_t)row * DD + ks * 32 + kg * 8;
                float4 u0 = *reinterpret_cast<const float4*>(p);
                float4 u1 = *reinterpret_cast<const float4*>(p + 4);
                half8 s;
                s[0] = (_Float16)u0.x; s[1] = (_Float16)u0.y;
                s[2] = (_Float16)u0.z; s[3] = (_Float16)u0.w;
                s[4] = (_Float16)u1.x; s[5] = (_Float16)u1.y;
                s[6] = (_Float16)u1.z; s[7] = (_Float16)u1.w;
                afrag[ks] = s;
            }
        }
    }

    for (int w = 0; w < 3; w++) {
        __syncthreads();  // previous epilogue reads done
        const ushort* Wb = Wt + (size_t)w * DD * DD;
#pragma unroll
        for (int i = 0; i < 8; i++) {
            int flat = i * 256 + t;       // 0..2047 chunks of 8 shorts
            int row = flat >> 4, ch = flat & 15;
            half8 v = *reinterpret_cast<const half8*>(Wb + row * DD + ch * 8);
            *reinterpret_cast<half8*>(&wsh[row * 136 + ch * 8]) = v;
        }
        __syncthreads();

        f32x4 acc[8];
#pragma unroll
        for (int ng = 0; ng < 8; ng++) acc[ng] = (f32x4)(0.f);

#pragma unroll
        for (int ks = 0; ks < 4; ks++) {
#pragma unroll
            for (int ng = 0; ng < 8; ng++) {
                half8 bfrag = *reinterpret_cast<const half8*>(
                    &wsh[(ng * 16 + qrow) * 136 + ks * 32 + kg * 8]);
                acc[ng] = __builtin_amdgcn_mfma_f32_16x16x32_f16(
                    afrag[ks], bfrag, acc[ng], 0, 0, 0);
            }
        }

        // ---- LDS-transpose epilogue ----
        __syncthreads();  // all waves done reading weights from wsh
        // acc rows: lds row = wid*16 + kg*4 + r, col = ng*16 + qrow
#pragma unroll
        for (int r = 0; r < 4; r++) {
            int lrow = wid * 16 + kg * 4 + r;
#pragma unroll
            for (int ng = 0; ng < 8; ng++)
                wsh[lrow * 136 + ng * 16 + qrow] = f2h(acc[ng][r]);
        }
        __syncthreads();
        // coalesced read-back + half8 stores: 4 chunks of 16B per thread
        ushort* Ob = (w == 0) ? O0b : (w == 1) ? O1b : O2b;
#pragma unroll
        for (int i = 0; i < 4; i++) {
            int flat = i * 64 + lane;          // 0..255 within this wave's 16-row stripe
            int lrow = flat >> 4;              // 0..15
            int ch = flat & 15;
            int grow = m0 + lrow;
            if (grow < NN) {
                half8 v = *reinterpret_cast<const half8*>(
                    &wsh[(wid * 16 + lrow) * 136 + ch * 8]);
                *reinterpret_cast<half8*>(Ob + (size_t)grow * DD + ch * 8) = v;
            }
        }
    }
}

// ---------------- fused logits + softmax (no-max) + aggregate + combine (+relu) ----------------
// 2 waves/block, one node/wave; quarter-wave per edge; coalesced index preload + shfl
// broadcast; uniform trip counts; unroll-2; packed half2 math. (R12 structure — measured
// at the pull-gather FETCH floor: ~88-92 MB compulsory per-XCD traffic @ ~2.1 TB/s.)
template <int OUTVEC>
__global__ __launch_bounds__(128) void k_fused(
    const int* __restrict__ offs, const int* __restrict__ csr_src,
    const ushort* __restrict__ xlb,  // [NN][128] fp16 (messages + logit left)
    const ushort* __restrict__ xrb,  // [NN][128] fp16 (logit right)
    const float* __restrict__ att,
    const ushort* __restrict__ linb, // [NN][128] fp16 (skip connection)
    const float* __restrict__ bb,
    const float* __restrict__ blin, ushort* __restrict__ houtb,
    const float* __restrict__ Wlo, const float* __restrict__ Wro,
    const float* __restrict__ Wlino, const float* __restrict__ blino,
    float* __restrict__ xlo, float* __restrict__ xro, float* __restrict__ lino) {
    int wid = blockIdx.x * 2 + (threadIdx.x >> 6);  // one node per wave
    if (wid >= NN) return;
    int lane = threadIdx.x & 63;
    int q = lane >> 4;    // quarter 0..3
    int ql = lane & 15;
    int c0 = ql * 8;

    __half2 av6h[4], av4h[4];
    {
        float4 a0 = *reinterpret_cast<const float4*>(att + c0);
        float4 a1 = *reinterpret_cast<const float4*>(att + c0 + 4);
        float av[8] = {a0.x, a0.y, a0.z, a0.w, a1.x, a1.y, a1.z, a1.w};
#pragma unroll
        for (int c = 0; c < 4; c++) {
            av6h[c] = __halves2half2(__float2half(0.6f * av[2 * c]),
                                     __float2half(0.6f * av[2 * c + 1]));
            av4h[c] = __halves2half2(__float2half(0.4f * av[2 * c]),
                                     __float2half(0.4f * av[2 * c + 1]));
        }
    }
    __half2 xrv2[4];
    {
        uint4 xrp = *reinterpret_cast<const uint4*>(xrb + (size_t)wid * DD + c0);
        xrv2[0] = u2h2(xrp.x); xrv2[1] = u2h2(xrp.y);
        xrv2[2] = u2h2(xrp.z); xrv2[3] = u2h2(xrp.w);
    }

    int start = offs[wid];
    int deg = offs[wid + 1] - start;

    float ss = 0.f;
    __half2 acc2[4];
#pragma unroll
    for (int c = 0; c < 4; c++) acc2[c] = u2h2(0u);

    for (int eb = 0; eb < deg; eb += 64) {
        int nbv = min(64, deg - eb);
        int myidx = (lane < nbv) ? csr_src[start + eb + lane] : 0;
        int rounds = (nbv + 3) >> 2;
        int r = 0;
        // ---- unroll-2: two independent gathers in flight ----
        for (; r + 2 <= rounds; r += 2) {
            int j0 = r * 4 + q;          // always < nbv in this loop
            int j1 = j0 + 4;
            bool ok1 = j1 < nbv;
            int s0 = __shfl(myidx, j0, 64);
            int s1 = __shfl(myidx, j1, 64);
            uint4 xp0 = *reinterpret_cast<const uint4*>(xlb + (size_t)s0 * DD + c0);
            uint4 xp1 = *reinterpret_cast<const uint4*>(xlb + (size_t)s1 * DD + c0);
            __half2 xa[4] = {u2h2(xp0.x), u2h2(xp0.y), u2h2(xp0.z), u2h2(xp0.w)};
            __half2 xb[4] = {u2h2(xp1.x), u2h2(xp1.y), u2h2(xp1.z), u2h2(xp1.w)};
            __half2 va = u2h2(0u), vb = u2h2(0u);
#pragma unroll
            for (int c = 0; c < 4; c++) {
                __half2 ua = __hadd2(xa[c], xrv2[c]);
                __half2 ub = __hadd2(xb[c], xrv2[c]);
                __half2 aa = u2h2(h22u(ua) & 0x7fff7fffu);
                __half2 ab = u2h2(h22u(ub) & 0x7fff7fffu);
                va = __hfma2(ua, av6h[c], va);
                vb = __hfma2(ub, av6h[c], vb);
                va = __hfma2(aa, av4h[c], va);
                vb = __hfma2(ab, av4h[c], vb);
            }
            float v0 = __low2float(va) + __high2float(va);
            float v1 = __low2float(vb) + __high2float(vb);
#pragma unroll
            for (int msk = 1; msk < 16; msk <<= 1) {
                v0 += __shfl_xor(v0, msk, 64);
                v1 += __shfl_xor(v1, msk, 64);
            }
            float p0 = __expf(v0);
            float p1 = ok1 ? __expf(v1) : 0.f;
            ss += p0 + p1;
            __half2 p20 = __float2half2_rn(p0);
            __half2 p21 = __float2half2_rn(p1);
#pragma unroll
            for (int c = 0; c < 4; c++) {
                acc2[c] = __hfma2(p20, xa[c], acc2[c]);
                acc2[c] = __hfma2(p21, xb[c], acc2[c]);
            }
        }
        // ---- tail round ----
        if (r < rounds) {
            int j = r * 4 + q;
            bool ok = j < nbv;
            int s = __shfl(myidx, j, 64);
            uint4 xp = *reinterpret_cast<const uint4*>(xlb + (size_t)s * DD + c0);
            __half2 xv2[4] = {u2h2(xp.x), u2h2(xp.y), u2h2(xp.z), u2h2(xp.w)};
            __half2 vs = u2h2(0u);
#pragma unroll
            for (int c = 0; c < 4; c++) {
                __half2 u2 = __hadd2(xv2[c], xrv2[c]);
                __half2 a2 = u2h2(h22u(u2) & 0x7fff7fffu);
                vs = __hfma2(u2, av6h[c], vs);
                vs = __hfma2(a2, av4h[c], vs);
            }
            float v = __low2float(vs) + __high2float(vs);
#pragma unroll
            for (int msk = 1; msk < 16; msk <<= 1) v += __shfl_xor(v, msk, 64);
            float p = ok ? __expf(v) : 0.f;
            ss += p;
            __half2 p2 = __float2half2_rn(p);
#pragma unroll
            for (int c = 0; c < 4; c++) acc2[c] = __hfma2(p2, xv2[c], acc2[c]);
        }
    }

    // merge the 4 quarter-states (plain sums, no-max softmax)
#pragma unroll
    for (int msk = 16; msk < 64; msk <<= 1) {
        ss += __shfl_xor(ss, msk, 64);
#pragma unroll
        for (int c = 0; c < 4; c++) {
            unsigned int o = (unsigned int)__shfl_xor((int)h22u(acc2[c]), msk, 64);
            acc2[c] = __hadd2(acc2[c], u2h2(o));
        }
    }

    if (q == 0) {
        float inv = 1.f / (ss + 1e-16f);
        float o[8];
#pragma unroll
        for (int c = 0; c < 4; c++) {
            o[2 * c] = __low2float(acc2[c]) * inv;
            o[2 * c + 1] = __high2float(acc2[c]) * inv;
        }
        float lv[8];
        {
            uint4 lp = *reinterpret_cast<const uint4*>(linb + (size_t)wid * DD + c0);
            __half2 l2[4] = {u2h2(lp.x), u2h2(lp.y), u2h2(lp.z), u2h2(lp.w)};
#pragma unroll
            for (int c = 0; c < 4; c++) {
                lv[2 * c] = __low2float(l2[c]);
                lv[2 * c + 1] = __high2float(l2[c]);
            }
        }
        float4 b0 = *reinterpret_cast<const float4*>(bb + c0);
        float4 b1 = *reinterpret_cast<const float4*>(bb + c0 + 4);
        float4 bl0 = *reinterpret_cast<const float4*>(blin + c0);
        float4 bl1 = *reinterpret_cast<const float4*>(blin + c0 + 4);
        float bv[8] = {b0.x, b0.y, b0.z, b0.w, b1.x, b1.y, b1.z, b1.w};
        float blv[8] = {bl0.x, bl0.y, bl0.z, bl0.w, bl1.x, bl1.y, bl1.z, bl1.w};
#pragma unroll
        for (int c = 0; c < 8; c++) o[c] = fmaxf(o[c] + bv[c] + lv[c] + blv[c], 0.f);

        if (!OUTVEC) {
            uint4 pk;
            pk.x = (unsigned)f2h(o[0]) | ((unsigned)f2h(o[1]) << 16);
            pk.y = (unsigned)f2h(o[2]) | ((unsigned)f2h(o[3]) << 16);
            pk.z = (unsigned)f2h(o[4]) | ((unsigned)f2h(o[5]) << 16);
            pk.w = (unsigned)f2h(o[6]) | ((unsigned)f2h(o[7]) << 16);
            *reinterpret_cast<uint4*>(houtb + (size_t)wid * DD + c0) = pk;
        } else {
            // fused output-layer matvecs: d = h . W (128-length dots)
            float4 w0a = *reinterpret_cast<const float4*>(Wlo + c0);
            float4 w0b = *reinterpret_cast<const float4*>(Wlo + c0 + 4);
            float4 w1a = *reinterpret_cast<const float4*>(Wro + c0);
            float4 w1b = *reinterpret_cast<const float4*>(Wro + c0 + 4);
            float4 w2a = *reinterpret_cast<const float4*>(Wlino + c0);
            float4 w2b = *reinterpret_cast<const float4*>(Wlino + c0 + 4);
            float wv0[8] = {w0a.x, w0a.y, w0a.z, w0a.w, w0b.x, w0b.y, w0b.z, w0b.w};
            float wv1[8] = {w1a.x, w1a.y, w1a.z, w1a.w, w1b.x, w1b.y, w1b.z, w1b.w};
            float wv2[8] = {w2a.x, w2a.y, w2a.z, w2a.w, w2b.x, w2b.y, w2b.z, w2b.w};
            float d0 = 0.f, d1 = 0.f, d2 = 0.f;
#pragma unroll
            for (int c = 0; c < 8; c++) {
                d0 += o[c] * wv0[c];
                d1 += o[c] * wv1[c];
                d2 += o[c] * wv2[c];
            }
#pragma unroll
            for (int msk = 1; msk < 16; msk <<= 1) {
                d0 += __shfl_xor(d0, msk, 64);
                d1 += __shfl_xor(d1, msk, 64);
                d2 += __shfl_xor(d2, msk, 64);
            }
            if (ql == 0) {
                xlo[wid] = d0;
                xro[wid] = d1;
                lino[wid] = d2 + blino[0];
            }
        }
    }
}

// ---------------- fused output-layer logits + softmax (no-max) + aggregate ----------------
// 4 nodes per wave (16 lanes each): avg degree 16 -> one pass per node, no idle 48 lanes.
__global__ __launch_bounds__(256) void k_aggout(
    const int* __restrict__ offs, const int* __restrict__ csr_src,
    const float* __restrict__ xlo, const float* __restrict__ xro,
    const float* __restrict__ atto, const float* __restrict__ lino,
    const float* __restrict__ bo, float* __restrict__ out) {
    int lane = threadIdx.x & 63;
    int g = lane >> 4;          // 16-lane group 0..3
    int gl = lane & 15;
    int wid = (blockIdx.x * blockDim.x + threadIdx.x) / 64 * 4 + g;  // node per group
    if (wid >= NN) return;
    int start = offs[wid];
    int deg = offs[wid + 1] - start;
    float xro_w = xro[wid];
    float a0 = atto[0];

    float sl = 0.f, nl = 0.f;
    for (int j = gl; j < deg; j += 16) {
        int s = csr_src[start + j];
        float xs = xlo[s];
        float u = xs + xro_w;
        float e = fmaxf(u, SLOPE * u) * a0;
        float p = __expf(e);
        sl += p;
        nl += p * xs;
    }
#pragma unroll
    for (int msk = 1; msk < 16; msk <<= 1) {
        sl += __shfl_xor(sl, msk, 64);
        nl += __shfl_xor(nl, msk, 64);
    }
    if (gl == 0) out[wid] = nl / (sl + 1e-16f) + bo[0] + lino[wid];
}

extern "C" void kernel_launch(void* const* d_in, const int* in_sizes, int n_in,
                              void* d_out, int out_size, void* d_ws, size_t ws_size,
                              hipStream_t stream) {
    const float* x = (const float*)d_in[0];
    const int* ei = (const int*)d_in[1];
    const int* srcv = ei;
    const int* dstv = ei + EE;
    const float* Wl1 = (const float*)d_in[2];
    const float* Wr1 = (const float*)d_in[3];
    const float* att1 = (const float*)d_in[4];
    const float* b1 = (const float*)d_in[5];
    const float* Wlin1 = (const float*)d_in[6];
    const float* blin1 = (const float*)d_in[7];
    const float* Wl2 = (const float*)d_in[8];
    const float* Wr2 = (const float*)d_in[9];
    const float* att2 = (const float*)d_in[10];
    const float* b2 = (const float*)d_in[11];
    const float* Wlin2 = (const float*)d_in[12];
    const float* blin2 = (const float*)d_in[13];
    const float* Wlo = (const float*)d_in[14];
    const float* Wro = (const float*)d_in[15];
    const float* atto = (const float*)d_in[16];
    const float* bo = (const float*)d_in[17];
    const float* Wlino = (const float*)d_in[18];
    const float* blino = (const float*)d_in[19];

    char* w = (char*)d_ws;
    auto alloc = [&](size_t bytes) {
        void* p = (void*)w;
        w += (bytes + 255) & ~(size_t)255;
        return p;
    };
    ushort* xlb = (ushort*)alloc((size_t)NN * DD * 2);   // fp16 messages
    ushort* xrb = (ushort*)alloc((size_t)NN * DD * 2);   // fp16 logit-right
    ushort* linb = (ushort*)alloc((size_t)NN * DD * 2);  // fp16 skip
    ushort* hb = (ushort*)alloc((size_t)NN * DD * 2);    // hidden state, fp16
    ushort* Wt = (ushort*)alloc((size_t)6 * DD * DD * 2);
    float* xlo = (float*)alloc((size_t)NN * 4);
    float* xro = (float*)alloc((size_t)NN * 4);
    float* lino = (float*)alloc((size_t)NN * 4);
    int* deg = (int*)alloc((size_t)NN * 4);
    int* offs = (int*)alloc((size_t)(NN + 1) * 4);
    int* cursor = (int*)alloc((size_t)NN * 4);
    int* bsum = (int*)alloc(256 * 4);
    int* boff = (int*)alloc(256 * 4);
    int* csr_src = (int*)alloc((size_t)(EE + 64) * 4);

    const int NB = (NN + 255) / 256;  // 196

    // CSR build (parallel 3-kernel scan; cursor from scan, no epos round-trip)
    hipMemsetAsync(deg, 0, (size_t)NN * 4, stream);
    k_degree<<<(EE + 255) / 256, 256, 0, stream>>>(dstv, deg);
    k_blocksum<<<NB, 256, 0, stream>>>(deg, bsum);
    k_scan_bsum<<<1, 256, 0, stream>>>(bsum, boff, NB);
    k_scan_final<<<NB, 256, 0, stream>>>(deg, boff, offs, cursor);
    k_scatter<<<(EE + 255) / 256, 256, 0, stream>>>(srcv, dstv, cursor, csr_src);

    // weights -> transposed fp16
    k_wconvert<<<(6 * DD * DD) / 256, 256, 0, stream>>>(Wl1, Wr1, Wlin1, Wl2, Wr2, Wlin2, Wt);

    const int GEMM_GRID = (NN + 63) / 64;            // 782 (~3.05 blocks/CU)
    const int FUSED_GRID = (NN + 1) / 2;             // 25000 (2 waves/block)
    const int AGGOUT_GRID = (NN + 15) / 16;          // 3125 (16 nodes/block)

    // layer 1
    k_gemm3m<0><<<GEMM_GRID, 256, 0, stream>>>(x, nullptr, Wt + (size_t)0 * 3 * DD * DD,
                                               xlb, xrb, linb);
    k_fused<0><<<FUSED_GRID, 128, 0, stream>>>(offs, csr_src, xlb, xrb, att1, linb, b1, blin1, hb,
                                               nullptr, nullptr, nullptr, nullptr,
                                               nullptr, nullptr, nullptr);
    // layer 2 (+fused output matvecs)
    k_gemm3m<1><<<GEMM_GRID, 256, 0, stream>>>(nullptr, hb, Wt + (size_t)1 * 3 * DD * DD,
                                               xlb, xrb, linb);
    k_fused<1><<<FUSED_GRID, 128, 0, stream>>>(offs, csr_src, xlb, xrb, att2, linb, b2, blin2,
                                               nullptr, Wlo, Wro, Wlino, blino,
                                               xlo, xro, lino);
    // output layer aggregation
    k_aggout<<<AGGOUT_GRID, 256, 0, stream>>>(offs, csr_src, xlo, xro, atto, lino, bo,
                                              (float*)d_out);
}

// Round 16
// 188.262 us; speedup vs baseline: 1.1823x; 1.1823x over previous
//
#include <hip/hip_runtime.h>
#include <hip/hip_fp16.h>
#include <math.h>

#define NN 50000
#define EE 800000
#define DD 128
#define SLOPE 0.2f

typedef __attribute__((ext_vector_type(8))) _Float16 half8;  // 8 fp16 (4 VGPRs)
typedef __attribute__((ext_vector_type(4))) float f32x4;     // MFMA acc

static __device__ __forceinline__ ushort f2h(float f) {
    __half h = __float2half(f);
    return *reinterpret_cast<ushort*>(&h);
}
static __device__ __forceinline__ __half2 u2h2(unsigned int u) {
    __half2 h;
    *reinterpret_cast<unsigned int*>(&h) = u;
    return h;
}
static __device__ __forceinline__ unsigned int h22u(__half2 h) {
    return *reinterpret_cast<unsigned int*>(&h);
}

// ---------------- CSR build (split scheme: atomic capture in degree, non-atomic scatter) ----------------
__global__ void k_degree(const int* __restrict__ dstv, int* __restrict__ deg,
                         int* __restrict__ epos) {
    int i = blockIdx.x * blockDim.x + threadIdx.x;
    if (i < EE) epos[i] = atomicAdd(&deg[dstv[i]], 1);
}

__global__ void k_blocksum(const int* __restrict__ deg, int* __restrict__ bsum) {
    int t = threadIdx.x;
    int idx = blockIdx.x * 256 + t;
    int v = (idx < NN) ? deg[idx] : 0;
#pragma unroll
    for (int m = 1; m < 64; m <<= 1) v += __shfl_xor(v, m, 64);
    __shared__ int part[4];
    if ((t & 63) == 0) part[t >> 6] = v;
    __syncthreads();
    if (t == 0) bsum[blockIdx.x] = part[0] + part[1] + part[2] + part[3];
}

__global__ void k_scan_bsum(const int* __restrict__ bsum, int* __restrict__ boff, int nb) {
    __shared__ int sd[2][256];
    int t = threadIdx.x;
    int v = (t < nb) ? bsum[t] : 0;
    sd[0][t] = v;
    __syncthreads();
    int s = 0;
    for (int off = 1; off < 256; off <<= 1) {
        int x = sd[s][t];
        if (t >= off) x += sd[s][t - off];
        sd[s ^ 1][t] = x;
        s ^= 1;
        __syncthreads();
    }
    if (t < nb) boff[t] = sd[s][t] - v;  // exclusive
}

__global__ void k_scan_final(const int* __restrict__ deg, const int* __restrict__ boff,
                             int* __restrict__ offs) {
    __shared__ int sd[2][256];
    int t = threadIdx.x;
    int idx = blockIdx.x * 256 + t;
    int v = (idx < NN) ? deg[idx] : 0;
    sd[0][t] = v;
    __syncthreads();
    int s = 0;
    for (int off = 1; off < 256; off <<= 1) {
        int x = sd[s][t];
        if (t >= off) x += sd[s][t - off];
        sd[s ^ 1][t] = x;
        s ^= 1;
        __syncthreads();
    }
    int incl = sd[s][t];
    int base = boff[blockIdx.x];
    if (idx < NN) offs[idx + 1] = base + incl;
    if (idx == 0) offs[0] = 0;
}

__global__ void k_scatter(const int* __restrict__ srcv, const int* __restrict__ dstv,
                          const int* __restrict__ offs, const int* __restrict__ epos,
                          int* __restrict__ csr_src) {
    int i = blockIdx.x * blockDim.x + threadIdx.x;
    if (i < EE) csr_src[offs[dstv[i]] + epos[i]] = srcv[i];
}

// ---------------- weight convert: Wt[i][n][k] = fp16(W_i[k][n]) ----------------
__global__ __launch_bounds__(256) void k_wconvert(
    const float* __restrict__ W0, const float* __restrict__ W1, const float* __restrict__ W2,
    const float* __restrict__ W3, const float* __restrict__ W4, const float* __restrict__ W5,
    ushort* __restrict__ Wt) {
    int idx = blockIdx.x * 256 + threadIdx.x;  // 6*16384
    int i = idx >> 14;
    int r = idx & 16383;
    int n = r >> 7;
    int k = r & 127;
    const float* Ws[6] = {W0, W1, W2, W3, W4, W5};
    Wt[idx] = f2h(Ws[i][k * DD + n]);
}

// ---------------- MFMA 3-matrix GEMM (fp16 in, fp32 acc), 64-row tiles ----------------
// block=256 (4 waves), each wave: 16 rows x 128 cols. K=128. grid=(NN+63)/64=782
// (~3.05 blocks/CU). LDS-transpose epilogue for coalesced half8 stores.
template <int XBF>
__global__ __launch_bounds__(256) void k_gemm3m(
    const float* __restrict__ Xf,     // [NN][128] fp32   (XBF=0)
    const ushort* __restrict__ Xb,    // [NN][128] fp16   (XBF=1)
    const ushort* __restrict__ Wt,    // [3][128][128] fp16, [n][k] layout
    ushort* __restrict__ O0b,         // xl fp16
    ushort* __restrict__ O1b,         // xr fp16
    ushort* __restrict__ O2b) {       // lin fp16
    __shared__ ushort wsh[128 * 136];  // weights tile; reused as epilogue transpose buffer
    int t = threadIdx.x;
    int wid = t >> 6, lane = t & 63;
    int m0 = blockIdx.x * 64 + wid * 16;
    int qrow = lane & 15, kg = lane >> 4;

    // A fragments: 4 k-steps, row = m0 + qrow
    half8 afrag[4];
    {
        int row = m0 + qrow;
        row = (row < NN) ? row : (NN - 1);  // clamp (stores predicated)
#pragma unroll
        for (int ks = 0; ks < 4; ks++) {
            if (XBF) {
                afrag[ks] = *reinterpret_cast<const half8*>(
                    Xb + (size_t)row * DD + ks * 32 + kg * 8);
            } else {
                const float* p = Xf + (size_t)row * DD + ks * 32 + kg * 8;
                float4 u0 = *reinterpret_cast<const float4*>(p);
                float4 u1 = *reinterpret_cast<const float4*>(p + 4);
                half8 s;
                s[0] = (_Float16)u0.x; s[1] = (_Float16)u0.y;
                s[2] = (_Float16)u0.z; s[3] = (_Float16)u0.w;
                s[4] = (_Float16)u1.x; s[5] = (_Float16)u1.y;
                s[6] = (_Float16)u1.z; s[7] = (_Float16)u1.w;
                afrag[ks] = s;
            }
        }
    }

    for (int w = 0; w < 3; w++) {
        __syncthreads();  // previous epilogue reads done
        const ushort* Wb = Wt + (size_t)w * DD * DD;
#pragma unroll
        for (int i = 0; i < 8; i++) {
            int flat = i * 256 + t;       // 0..2047 chunks of 8 shorts
            int row = flat >> 4, ch = flat & 15;
            half8 v = *reinterpret_cast<const half8*>(Wb + row * DD + ch * 8);
            *reinterpret_cast<half8*>(&wsh[row * 136 + ch * 8]) = v;
        }
        __syncthreads();

        f32x4 acc[8];
#pragma unroll
        for (int ng = 0; ng < 8; ng++) acc[ng] = (f32x4)(0.f);

#pragma unroll
        for (int ks = 0; ks < 4; ks++) {
#pragma unroll
            for (int ng = 0; ng < 8; ng++) {
                half8 bfrag = *reinterpret_cast<const half8*>(
                    &wsh[(ng * 16 + qrow) * 136 + ks * 32 + kg * 8]);
                acc[ng] = __builtin_amdgcn_mfma_f32_16x16x32_f16(
                    afrag[ks], bfrag, acc[ng], 0, 0, 0);
            }
        }

        // ---- LDS-transpose epilogue ----
        __syncthreads();  // all waves done reading weights from wsh
#pragma unroll
        for (int r = 0; r < 4; r++) {
            int lrow = wid * 16 + kg * 4 + r;
#pragma unroll
            for (int ng = 0; ng < 8; ng++)
                wsh[lrow * 136 + ng * 16 + qrow] = f2h(acc[ng][r]);
        }
        __syncthreads();
        ushort* Ob = (w == 0) ? O0b : (w == 1) ? O1b : O2b;
#pragma unroll
        for (int i = 0; i < 4; i++) {
            int flat = i * 64 + lane;          // 0..255 within this wave's 16-row stripe
            int lrow = flat >> 4;              // 0..15
            int ch = flat & 15;
            int grow = m0 + lrow;
            if (grow < NN) {
                half8 v = *reinterpret_cast<const half8*>(
                    &wsh[(wid * 16 + lrow) * 136 + ch * 8]);
                *reinterpret_cast<half8*>(Ob + (size_t)grow * DD + ch * 8) = v;
            }
        }
    }
}

// ---------------- fused logits + softmax (no-max) + aggregate + combine (+relu) ----------------
// 2 waves/block, one node/wave; quarter-wave per edge; coalesced index preload + shfl
// broadcast; uniform trip counts; unroll-2; packed half2 math. (At the pull-gather
// FETCH floor: ~88-92 MB compulsory per-XCD traffic @ ~2.1 TB/s.)
template <int OUTVEC>
__global__ __launch_bounds__(128) void k_fused(
    const int* __restrict__ offs, const int* __restrict__ csr_src,
    const ushort* __restrict__ xlb,  // [NN][128] fp16 (messages + logit left)
    const ushort* __restrict__ xrb,  // [NN][128] fp16 (logit right)
    const float* __restrict__ att,
    const ushort* __restrict__ linb, // [NN][128] fp16 (skip connection)
    const float* __restrict__ bb,
    const float* __restrict__ blin, ushort* __restrict__ houtb,
    const float* __restrict__ Wlo, const float* __restrict__ Wro,
    const float* __restrict__ Wlino, const float* __restrict__ blino,
    float* __restrict__ xlo, float* __restrict__ xro, float* __restrict__ lino) {
    int wid = blockIdx.x * 2 + (threadIdx.x >> 6);  // one node per wave
    if (wid >= NN) return;
    int lane = threadIdx.x & 63;
    int q = lane >> 4;    // quarter 0..3
    int ql = lane & 15;
    int c0 = ql * 8;

    __half2 av6h[4], av4h[4];
    {
        float4 a0 = *reinterpret_cast<const float4*>(att + c0);
        float4 a1 = *reinterpret_cast<const float4*>(att + c0 + 4);
        float av[8] = {a0.x, a0.y, a0.z, a0.w, a1.x, a1.y, a1.z, a1.w};
#pragma unroll
        for (int c = 0; c < 4; c++) {
            av6h[c] = __halves2half2(__float2half(0.6f * av[2 * c]),
                                     __float2half(0.6f * av[2 * c + 1]));
            av4h[c] = __halves2half2(__float2half(0.4f * av[2 * c]),
                                     __float2half(0.4f * av[2 * c + 1]));
        }
    }
    __half2 xrv2[4];
    {
        uint4 xrp = *reinterpret_cast<const uint4*>(xrb + (size_t)wid * DD + c0);
        xrv2[0] = u2h2(xrp.x); xrv2[1] = u2h2(xrp.y);
        xrv2[2] = u2h2(xrp.z); xrv2[3] = u2h2(xrp.w);
    }

    int start = offs[wid];
    int deg = offs[wid + 1] - start;

    float ss = 0.f;
    __half2 acc2[4];
#pragma unroll
    for (int c = 0; c < 4; c++) acc2[c] = u2h2(0u);

    for (int eb = 0; eb < deg; eb += 64) {
        int nbv = min(64, deg - eb);
        int myidx = (lane < nbv) ? csr_src[start + eb + lane] : 0;
        int rounds = (nbv + 3) >> 2;
        int r = 0;
        // ---- unroll-2: two independent gathers in flight ----
        for (; r + 2 <= rounds; r += 2) {
            int j0 = r * 4 + q;          // always < nbv in this loop
            int j1 = j0 + 4;
            bool ok1 = j1 < nbv;
            int s0 = __shfl(myidx, j0, 64);
            int s1 = __shfl(myidx, j1, 64);
            uint4 xp0 = *reinterpret_cast<const uint4*>(xlb + (size_t)s0 * DD + c0);
            uint4 xp1 = *reinterpret_cast<const uint4*>(xlb + (size_t)s1 * DD + c0);
            __half2 xa[4] = {u2h2(xp0.x), u2h2(xp0.y), u2h2(xp0.z), u2h2(xp0.w)};
            __half2 xb[4] = {u2h2(xp1.x), u2h2(xp1.y), u2h2(xp1.z), u2h2(xp1.w)};
            __half2 va = u2h2(0u), vb = u2h2(0u);
#pragma unroll
            for (int c = 0; c < 4; c++) {
                __half2 ua = __hadd2(xa[c], xrv2[c]);
                __half2 ub = __hadd2(xb[c], xrv2[c]);
                __half2 aa = u2h2(h22u(ua) & 0x7fff7fffu);
                __half2 ab = u2h2(h22u(ub) & 0x7fff7fffu);
                va = __hfma2(ua, av6h[c], va);
                vb = __hfma2(ub, av6h[c], vb);
                va = __hfma2(aa, av4h[c], va);
                vb = __hfma2(ab, av4h[c], vb);
            }
            float v0 = __low2float(va) + __high2float(va);
            float v1 = __low2float(vb) + __high2float(vb);
#pragma unroll
            for (int msk = 1; msk < 16; msk <<= 1) {
                v0 += __shfl_xor(v0, msk, 64);
                v1 += __shfl_xor(v1, msk, 64);
            }
            float p0 = __expf(v0);
            float p1 = ok1 ? __expf(v1) : 0.f;
            ss += p0 + p1;
            __half2 p20 = __float2half2_rn(p0);
            __half2 p21 = __float2half2_rn(p1);
#pragma unroll
            for (int c = 0; c < 4; c++) {
                acc2[c] = __hfma2(p20, xa[c], acc2[c]);
                acc2[c] = __hfma2(p21, xb[c], acc2[c]);
            }
        }
        // ---- tail round ----
        if (r < rounds) {
            int j = r * 4 + q;
            bool ok = j < nbv;
            int s = __shfl(myidx, j, 64);
            uint4 xp = *reinterpret_cast<const uint4*>(xlb + (size_t)s * DD + c0);
            __half2 xv2[4] = {u2h2(xp.x), u2h2(xp.y), u2h2(xp.z), u2h2(xp.w)};
            __half2 vs = u2h2(0u);
#pragma unroll
            for (int c = 0; c < 4; c++) {
                __half2 u2 = __hadd2(xv2[c], xrv2[c]);
                __half2 a2 = u2h2(h22u(u2) & 0x7fff7fffu);
                vs = __hfma2(u2, av6h[c], vs);
                vs = __hfma2(a2, av4h[c], vs);
            }
            float v = __low2float(vs) + __high2float(vs);
#pragma unroll
            for (int msk = 1; msk < 16; msk <<= 1) v += __shfl_xor(v, msk, 64);
            float p = ok ? __expf(v) : 0.f;
            ss += p;
            __half2 p2 = __float2half2_rn(p);
#pragma unroll
            for (int c = 0; c < 4; c++) acc2[c] = __hfma2(p2, xv2[c], acc2[c]);
        }
    }

    // merge the 4 quarter-states (plain sums, no-max softmax)
#pragma unroll
    for (int msk = 16; msk < 64; msk <<= 1) {
        ss += __shfl_xor(ss, msk, 64);
#pragma unroll
        for (int c = 0; c < 4; c++) {
            unsigned int o = (unsigned int)__shfl_xor((int)h22u(acc2[c]), msk, 64);
            acc2[c] = __hadd2(acc2[c], u2h2(o));
        }
    }

    if (q == 0) {
        float inv = 1.f / (ss + 1e-16f);
        float o[8];
#pragma unroll
        for (int c = 0; c < 4; c++) {
            o[2 * c] = __low2float(acc2[c]) * inv;
            o[2 * c + 1] = __high2float(acc2[c]) * inv;
        }
        float lv[8];
        {
            uint4 lp = *reinterpret_cast<const uint4*>(linb + (size_t)wid * DD + c0);
            __half2 l2[4] = {u2h2(lp.x), u2h2(lp.y), u2h2(lp.z), u2h2(lp.w)};
#pragma unroll
            for (int c = 0; c < 4; c++) {
                lv[2 * c] = __low2float(l2[c]);
                lv[2 * c + 1] = __high2float(l2[c]);
            }
        }
        float4 b0 = *reinterpret_cast<const float4*>(bb + c0);
        float4 b1 = *reinterpret_cast<const float4*>(bb + c0 + 4);
        float4 bl0 = *reinterpret_cast<const float4*>(blin + c0);
        float4 bl1 = *reinterpret_cast<const float4*>(blin + c0 + 4);
        float bv[8] = {b0.x, b0.y, b0.z, b0.w, b1.x, b1.y, b1.z, b1.w};
        float blv[8] = {bl0.x, bl0.y, bl0.z, bl0.w, bl1.x, bl1.y, bl1.z, bl1.w};
#pragma unroll
        for (int c = 0; c < 8; c++) o[c] = fmaxf(o[c] + bv[c] + lv[c] + blv[c], 0.f);

        if (!OUTVEC) {
            uint4 pk;
            pk.x = (unsigned)f2h(o[0]) | ((unsigned)f2h(o[1]) << 16);
            pk.y = (unsigned)f2h(o[2]) | ((unsigned)f2h(o[3]) << 16);
            pk.z = (unsigned)f2h(o[4]) | ((unsigned)f2h(o[5]) << 16);
            pk.w = (unsigned)f2h(o[6]) | ((unsigned)f2h(o[7]) << 16);
            *reinterpret_cast<uint4*>(houtb + (size_t)wid * DD + c0) = pk;
        } else {
            // fused output-layer matvecs: d = h . W (128-length dots)
            float4 w0a = *reinterpret_cast<const float4*>(Wlo + c0);
            float4 w0b = *reinterpret_cast<const float4*>(Wlo + c0 + 4);
            float4 w1a = *reinterpret_cast<const float4*>(Wro + c0);
            float4 w1b = *reinterpret_cast<const float4*>(Wro + c0 + 4);
            float4 w2a = *reinterpret_cast<const float4*>(Wlino + c0);
            float4 w2b = *reinterpret_cast<const float4*>(Wlino + c0 + 4);
            float wv0[8] = {w0a.x, w0a.y, w0a.z, w0a.w, w0b.x, w0b.y, w0b.z, w0b.w};
            float wv1[8] = {w1a.x, w1a.y, w1a.z, w1a.w, w1b.x, w1b.y, w1b.z, w1b.w};
            float wv2[8] = {w2a.x, w2a.y, w2a.z, w2a.w, w2b.x, w2b.y, w2b.z, w2b.w};
            float d0 = 0.f, d1 = 0.f, d2 = 0.f;
#pragma unroll
            for (int c = 0; c < 8; c++) {
                d0 += o[c] * wv0[c];
                d1 += o[c] * wv1[c];
                d2 += o[c] * wv2[c];
            }
#pragma unroll
            for (int msk = 1; msk < 16; msk <<= 1) {
                d0 += __shfl_xor(d0, msk, 64);
                d1 += __shfl_xor(d1, msk, 64);
                d2 += __shfl_xor(d2, msk, 64);
            }
            if (ql == 0) {
                xlo[wid] = d0;
                xro[wid] = d1;
                lino[wid] = d2 + blino[0];
            }
        }
    }
}

// ---------------- fused output-layer logits + softmax (no-max) + aggregate ----------------
// 4 nodes per wave (16 lanes each): avg degree 16 -> one pass per node, no idle 48 lanes.
__global__ __launch_bounds__(256) void k_aggout(
    const int* __restrict__ offs, const int* __restrict__ csr_src,
    const float* __restrict__ xlo, const float* __restrict__ xro,
    const float* __restrict__ atto, const float* __restrict__ lino,
    const float* __restrict__ bo, float* __restrict__ out) {
    int lane = threadIdx.x & 63;
    int g = lane >> 4;          // 16-lane group 0..3
    int gl = lane & 15;
    int wid = (blockIdx.x * blockDim.x + threadIdx.x) / 64 * 4 + g;  // node per group
    if (wid >= NN) return;
    int start = offs[wid];
    int deg = offs[wid + 1] - start;
    float xro_w = xro[wid];
    float a0 = atto[0];

    float sl = 0.f, nl = 0.f;
    for (int j = gl; j < deg; j += 16) {
        int s = csr_src[start + j];
        float xs = xlo[s];
        float u = xs + xro_w;
        float e = fmaxf(u, SLOPE * u) * a0;
        float p = __expf(e);
        sl += p;
        nl += p * xs;
    }
#pragma unroll
    for (int msk = 1; msk < 16; msk <<= 1) {
        sl += __shfl_xor(sl, msk, 64);
        nl += __shfl_xor(nl, msk, 64);
    }
    if (gl == 0) out[wid] = nl / (sl + 1e-16f) + bo[0] + lino[wid];
}

extern "C" void kernel_launch(void* const* d_in, const int* in_sizes, int n_in,
                              void* d_out, int out_size, void* d_ws, size_t ws_size,
                              hipStream_t stream) {
    const float* x = (const float*)d_in[0];
    const int* ei = (const int*)d_in[1];
    const int* srcv = ei;
    const int* dstv = ei + EE;
    const float* Wl1 = (const float*)d_in[2];
    const float* Wr1 = (const float*)d_in[3];
    const float* att1 = (const float*)d_in[4];
    const float* b1 = (const float*)d_in[5];
    const float* Wlin1 = (const float*)d_in[6];
    const float* blin1 = (const float*)d_in[7];
    const float* Wl2 = (const float*)d_in[8];
    const float* Wr2 = (const float*)d_in[9];
    const float* att2 = (const float*)d_in[10];
    const float* b2 = (const float*)d_in[11];
    const float* Wlin2 = (const float*)d_in[12];
    const float* blin2 = (const float*)d_in[13];
    const float* Wlo = (const float*)d_in[14];
    const float* Wro = (const float*)d_in[15];
    const float* atto = (const float*)d_in[16];
    const float* bo = (const float*)d_in[17];
    const float* Wlino = (const float*)d_in[18];
    const float* blino = (const float*)d_in[19];

    char* w = (char*)d_ws;
    auto alloc = [&](size_t bytes) {
        void* p = (void*)w;
        w += (bytes + 255) & ~(size_t)255;
        return p;
    };
    ushort* xlb = (ushort*)alloc((size_t)NN * DD * 2);   // fp16 messages
    ushort* xrb = (ushort*)alloc((size_t)NN * DD * 2);   // fp16 logit-right
    ushort* linb = (ushort*)alloc((size_t)NN * DD * 2);  // fp16 skip
    ushort* hb = (ushort*)alloc((size_t)NN * DD * 2);    // hidden state, fp16
    ushort* Wt = (ushort*)alloc((size_t)6 * DD * DD * 2);
    float* xlo = (float*)alloc((size_t)NN * 4);
    float* xro = (float*)alloc((size_t)NN * 4);
    float* lino = (float*)alloc((size_t)NN * 4);
    int* deg = (int*)alloc((size_t)NN * 4);
    int* offs = (int*)alloc((size_t)(NN + 1) * 4);
    int* bsum = (int*)alloc(256 * 4);
    int* boff = (int*)alloc(256 * 4);
    int* csr_src = (int*)alloc((size_t)(EE + 64) * 4);
    int* epos = (int*)alloc((size_t)EE * 4);

    const int NB = (NN + 255) / 256;  // 196

    // CSR build (split scheme: atomic capture in k_degree, non-atomic scatter — R14-verified)
    hipMemsetAsync(deg, 0, (size_t)NN * 4, stream);
    k_degree<<<(EE + 255) / 256, 256, 0, stream>>>(dstv, deg, epos);
    k_blocksum<<<NB, 256, 0, stream>>>(deg, bsum);
    k_scan_bsum<<<1, 256, 0, stream>>>(bsum, boff, NB);
    k_scan_final<<<NB, 256, 0, stream>>>(deg, boff, offs);
    k_scatter<<<(EE + 255) / 256, 256, 0, stream>>>(srcv, dstv, offs, epos, csr_src);

    // weights -> transposed fp16
    k_wconvert<<<(6 * DD * DD) / 256, 256, 0, stream>>>(Wl1, Wr1, Wlin1, Wl2, Wr2, Wlin2, Wt);

    const int GEMM_GRID = (NN + 63) / 64;            // 782 (~3.05 blocks/CU)
    const int FUSED_GRID = (NN + 1) / 2;             // 25000 (2 waves/block)
    const int AGGOUT_GRID = (NN + 15) / 16;          // 3125 (16 nodes/block)

    // layer 1
    k_gemm3m<0><<<GEMM_GRID, 256, 0, stream>>>(x, nullptr, Wt + (size_t)0 * 3 * DD * DD,
                                               xlb, xrb, linb);
    k_fused<0><<<FUSED_GRID, 128, 0, stream>>>(offs, csr_src, xlb, xrb, att1, linb, b1, blin1, hb,
                                               nullptr, nullptr, nullptr, nullptr,
                                               nullptr, nullptr, nullptr);
    // layer 2 (+fused output matvecs)
    k_gemm3m<1><<<GEMM_GRID, 256, 0, stream>>>(nullptr, hb, Wt + (size_t)1 * 3 * DD * DD,
                                               xlb, xrb, linb);
    k_fused<1><<<FUSED_GRID, 128, 0, stream>>>(offs, csr_src, xlb, xrb, att2, linb, b2, blin2,
                                               nullptr, Wlo, Wro, Wlino, blino,
                                               xlo, xro, lino);
    // output layer aggregation
    k_aggout<<<AGGOUT_GRID, 256, 0, stream>>>(offs, csr_src, xlo, xro, atto, lino, bo,
                                              (float*)d_out);
}